// Round 10
// baseline (397.306 us; speedup 1.0000x reference)
//
#include <hip/hip_runtime.h>

#define LBL 32
#define NPIX (736 * 736)   // 541696
#define NQ (NPIX / 4)      // 135424 = 529*256 exactly
#define NGRP 529           // 256-quad groups per batch (exact)
#define BATCH 8
#define DELTA_AGG 0.5f
#define DELTA_DIS 1.5f
#define REG_W 0.001f

// ---------- fused geometry (r8/r9-verified compute structure) ----------
#define QPT 6              // quad-groups per thread (24 px in named regs)
#define NBB 89             // 89*6=534 >= 529; grid 89*8=712 <= 768 (3 blk/CU)
#define NBLK (NBB * BATCH) // 712 blocks — co-resident by construction
#define FPA_BASE 1600000
#define FRED_BASE (FPA_BASE + BATCH * NBB * 192)   // +136704
#define FPC_BASE (FRED_BASE + BATCH * 256)
#define FBAR_BASE 1800000  // 3 x u32, memset to 0 each launch

__device__ __forceinline__ unsigned short f2bf(float f) {  // RTNE
  unsigned int u = __float_as_uint(f);
  unsigned int r = u + 0x7FFFu + ((u >> 16) & 1u);
  return (unsigned short)(r >> 16);
}
__device__ __forceinline__ float bfl(unsigned int w) {
  return __uint_as_float(w << 16);
}
__device__ __forceinline__ float bfh(unsigned int w) {
  return __uint_as_float(w & 0xFFFF0000u);
}

// ============================================================================
// ROUND-10 CHANGE (single variable): amdgpu_waves_per_eu(3,3).
// r8+r9 both landed at VGPR_Count=68 regardless of call/no-call — the
// backend's occupancy HEURISTIC targets ~7 waves/EU and spills the ~54-VGPR
// held pixel state to scratch (scratch sits in per-XCD L2: 0.7MB WRITE_SIZE,
// no HBM signature, ~200cy per access -> 290us). launch_bounds' 2nd arg is
// only a waves/EU FLOOR; waves_per_eu(3,3) also sets the CEILING, so the
// allocator gets a 512/3=170-VGPR budget with nothing to gain by spilling.
// Co-residency: 3 blocks/CU x 256 CU = 768 >= 712 (barrier deadlock-free,
// empirically passed in r9).
// ============================================================================
__device__ __forceinline__ void gridbar(unsigned int* bar, unsigned int tgt) {
  __syncthreads();  // all waves of block arrived; vmem drained
  if (threadIdx.x == 0) {
    __hip_atomic_fetch_add(bar, 1u, __ATOMIC_RELEASE, __HIP_MEMORY_SCOPE_AGENT);
    while (__hip_atomic_load(bar, __ATOMIC_ACQUIRE, __HIP_MEMORY_SCOPE_AGENT) < tgt) {
      __builtin_amdgcn_s_sleep(16);
    }
  }
  __syncthreads();
}

#define DOJ(J, SH, PK)                                                        \
  {                                                                           \
    const bool m = mv.J > 0.5f;                                               \
    const int li = m ? iv.J : 0;                                              \
    const bool kf = m && (kv.J > 0.5f);                                       \
    lw |= ((unsigned int)li) << (SH);                                         \
    PK.x = ((unsigned int)f2bf(e0.J)) | (((unsigned int)f2bf(e1.J)) << 16);   \
    PK.y = ((unsigned int)f2bf(e2.J)) | (((unsigned int)f2bf(e3.J)) << 16);   \
    if (li > 0) {                                                             \
      atomicAdd(&s_cta[li], 1.0f);                                            \
      if (kf) {                                                               \
        atomicAdd(&s_cnt[li], 1.0f);                                          \
        atomicAdd(&s_sum[0 * 33 + li], e0.J);                                 \
        atomicAdd(&s_sum[1 * 33 + li], e1.J);                                 \
        atomicAdd(&s_sum[2 * 33 + li], e2.J);                                 \
        atomicAdd(&s_sum[3 * 33 + li], e3.J);                                 \
      } else has0 = true;                                                     \
    } else has0 = true;                                                       \
  }

#define LOADG(G, IV, KV, MV, E0, E1, E2, E3)                                  \
  if (bx * QPT + (G) < NGRP) {                                                \
    const int q = (bx * QPT + (G)) * 256 + t;                                 \
    IV = ip[q]; KV = kp[q]; MV = mp[q];                                       \
    E0 = p0[q]; E1 = p1[q]; E2 = p2[q]; E3 = p3[q];                           \
  }

#define PROCG(G, IV, KV, MV, E0, E1, E2, E3, PKA, PKB, PKC, PKD, LWV)         \
  if (bx * QPT + (G) < NGRP) {                                                \
    const int4 iv = IV; const float4 kv = KV, mv = MV;                        \
    const float4 e0 = E0, e1 = E1, e2 = E2, e3 = E3;                          \
    unsigned int lw = 0;                                                      \
    DOJ(x, 0, PKA) DOJ(y, 8, PKB) DOJ(z, 16, PKC) DOJ(w, 24, PKD)             \
    LWV = lw;                                                                 \
  } else { LWV = 0; }

#define AGGJ(LW, SH, PK)                                                      \
  {                                                                           \
    const int li = ((LW) >> (SH)) & 0xFF;                                     \
    if (li > 0) {                                                             \
      const float d0 = bfl(PK.x) - s_mean[li * 4 + 0];                        \
      const float d1 = bfh(PK.x) - s_mean[li * 4 + 1];                        \
      const float d2 = bfl(PK.y) - s_mean[li * 4 + 2];                        \
      const float d3 = bfh(PK.y) - s_mean[li * 4 + 3];                        \
      const float sq = d0 * d0 + d1 * d1 + d2 * d2 + d3 * d3;                 \
      const float dist = (sq > 0.f) ? sqrtf(sq) : 0.f;                        \
      const float tt = fmaxf(dist - DELTA_AGG, 0.f);                          \
      atomicAdd(&s_val[li], logf(fmaf(tt, tt, 1.0f)));                        \
    }                                                                         \
  }

#define AGGG(G, PKA, PKB, PKC, PKD, LW)                                       \
  if (bx * QPT + (G) < NGRP) {                                                \
    AGGJ(LW, 0, PKA) AGGJ(LW, 8, PKB) AGGJ(LW, 16, PKC) AGGJ(LW, 24, PKD)     \
  }

__global__ __launch_bounds__(256)
__attribute__((amdgpu_waves_per_eu(3, 3)))
void kF(
    const float* __restrict__ emb, const int* __restrict__ inst,
    const float* __restrict__ kern, const float* __restrict__ mask,
    float* __restrict__ ws, float* __restrict__ out) {
  const int bx = blockIdx.x;  // 0..NBB-1
  const int by = blockIdx.y;  // batch
  const int t = threadIdx.x;
  unsigned int* bar = (unsigned int*)(ws + FBAR_BASE);

  __shared__ float s_cnt[LBL];      // [0] = "saw label 0" flag
  __shared__ float s_sum[4 * 33];   // padded [comp][label]
  __shared__ float s_cta[LBL];
  __shared__ float s_mean[LBL * 4];
  __shared__ float s_val[LBL];
  __shared__ float redl[LBL][9];
  __shared__ float sv[LBL];

  if (t < LBL) { s_cnt[t] = 0.f; s_cta[t] = 0.f; }
  if (t < 4 * 33) s_sum[t] = 0.f;
  __syncthreads();

  const long base = (long)by * NPIX;
  const float* ebase = emb + (long)by * 4 * NPIX;
  const int4* ip = (const int4*)(inst + base);
  const float4* kp = (const float4*)(kern + base);
  const float4* mp = (const float4*)(mask + base);
  const float4* p0 = (const float4*)(ebase);
  const float4* p1 = (const float4*)(ebase + NPIX);
  const float4* p2 = (const float4*)(ebase + 2 * NPIX);
  const float4* p3 = (const float4*)(ebase + 3 * NPIX);

  // held pixel state — named; VGPR budget now 170 via waves_per_eu(3,3)
  uint2 pk0a, pk0b, pk0c, pk0d, pk1a, pk1b, pk1c, pk1d;
  uint2 pk2a, pk2b, pk2c, pk2d, pk3a, pk3b, pk3c, pk3d;
  uint2 pk4a, pk4b, pk4c, pk4d, pk5a, pk5b, pk5c, pk5d;
  unsigned int lw0, lw1, lw2, lw3, lw4, lw5;
  bool has0 = false;

  // ping-pong load sets
  int4 ivA, ivB;
  float4 kvA, mvA, e0A, e1A, e2A, e3A;
  float4 kvB, mvB, e0B, e1B, e2B, e3B;

  // ---- Phase A: load + histogram + pack-to-registers (prefetch depth 2) ----
  LOADG(0, ivA, kvA, mvA, e0A, e1A, e2A, e3A)
  LOADG(1, ivB, kvB, mvB, e0B, e1B, e2B, e3B)
  PROCG(0, ivA, kvA, mvA, e0A, e1A, e2A, e3A, pk0a, pk0b, pk0c, pk0d, lw0)
  LOADG(2, ivA, kvA, mvA, e0A, e1A, e2A, e3A)
  PROCG(1, ivB, kvB, mvB, e0B, e1B, e2B, e3B, pk1a, pk1b, pk1c, pk1d, lw1)
  LOADG(3, ivB, kvB, mvB, e0B, e1B, e2B, e3B)
  PROCG(2, ivA, kvA, mvA, e0A, e1A, e2A, e3A, pk2a, pk2b, pk2c, pk2d, lw2)
  LOADG(4, ivA, kvA, mvA, e0A, e1A, e2A, e3A)
  PROCG(3, ivB, kvB, mvB, e0B, e1B, e2B, e3B, pk3a, pk3b, pk3c, pk3d, lw3)
  LOADG(5, ivB, kvB, mvB, e0B, e1B, e2B, e3B)
  PROCG(4, ivA, kvA, mvA, e0A, e1A, e2A, e3A, pk4a, pk4b, pk4c, pk4d, lw4)
  PROCG(5, ivB, kvB, mvB, e0B, e1B, e2B, e3B, pk5a, pk5b, pk5c, pk5d, lw5)

  if (has0) s_cnt[0] = 1.0f;  // benign race
  __syncthreads();
  {  // block-major coalesced partial store; linearize padded sums to l*4+c
    float* po = ws + FPA_BASE + ((size_t)by * NBB + bx) * 192;
    if (t < 192) {
      float v;
      if (t < 32) v = s_cnt[t];
      else if (t < 160) {
        const int e = t - 32;
        v = s_sum[(e & 3) * 33 + (e >> 2)];
      } else {
        v = s_cta[t - 160];
      }
      po[t] = v;
    }
  }

  gridbar(bar + 0, NBLK);

  // ---- Phase B: reduce partials; one wave per (batch, elem) column ----
  {
    const int gw = ((by * NBB + bx) << 2) + (t >> 6);  // 2848 waves >= 1536
    const int lane = t & 63;
    if (gw < BATCH * 192) {
      const int b = gw / 192, col = gw - b * 192;
      const float* pa = ws + FPA_BASE + (size_t)b * NBB * 192 + col;
      float s = 0.f;
      for (int g = lane; g < NBB; g += 64) s += pa[(size_t)g * 192];
#pragma unroll
      for (int o = 32; o > 0; o >>= 1) s += __shfl_down(s, o);
      if (lane == 0) ws[FRED_BASE + b * 256 + col] = s;  // raw totals
    }
  }

  gridbar(bar + 1, NBLK);

  // ---- Phase C: aggregation vals from REGISTERS (zero memory re-read) ----
  {
    const float* rd = ws + FRED_BASE + by * 256;
    if (t < LBL * 4) {
      const int l = t >> 2;
      s_mean[t] = (l == 0) ? 0.f : rd[32 + t] / fmaxf(rd[l], 1.0f);
    }
    if (t < LBL) s_val[t] = 0.f;
    __syncthreads();

    AGGG(0, pk0a, pk0b, pk0c, pk0d, lw0)
    AGGG(1, pk1a, pk1b, pk1c, pk1d, lw1)
    AGGG(2, pk2a, pk2b, pk2c, pk2d, lw2)
    AGGG(3, pk3a, pk3b, pk3c, pk3d, lw3)
    AGGG(4, pk4a, pk4b, pk4c, pk4d, lw4)
    AGGG(5, pk5a, pk5b, pk5c, pk5d, lw5)
    __syncthreads();
    if (t < 32) ws[FPC_BASE + ((size_t)by * NBB + bx) * 32 + t] = s_val[t];
  }

  gridbar(bar + 2, NBLK);

  // ---- Phase D: 8 blocks finalize (one per batch) ----
  if (by == 0 && bx < BATCH) {
    const int b2 = bx;
    const int col = t >> 3, sub = t & 7;  // 32 cols x 8 chunks
    const float* pc = ws + FPC_BASE + (size_t)b2 * NBB * 32 + col;
    float s = 0.f;
    for (int g = sub; g < NBB; g += 8) s += pc[(size_t)g * 32];
    redl[col][sub] = s;

    const float* rd2 = ws + FRED_BASE + b2 * 256;
    if (t < 128) {
      const int l = t >> 2;
      s_mean[t] = (l == 0) ? 0.f : rd2[32 + t] / fmaxf(rd2[l], 1.0f);
    } else if (t < 160) {
      s_cnt[t - 128] = rd2[t - 128];          // cnt_k (incl. label-0 flag)
    } else if (t < 192) {
      s_cta[t - 160] = rd2[160 + (t - 160)];  // cnt_a
    }
    __syncthreads();
    if (t < 32) {
      float v = 0.f;
#pragma unroll
      for (int k2 = 0; k2 < 8; k2++) v += redl[t][k2];
      sv[t] = v;
    }
    __syncthreads();

    if (t < 64) {  // wave 0 only
      const int lane = t;
      const bool pres = (lane < LBL) && (s_cnt[lane & 31] > 0.f);
      const unsigned long long bal_p = __ballot(pres);
      const int num_instance = __popcll(bal_p);
      const bool nz = pres && (lane > 0);
      const unsigned long long bal_nz = __ballot(nz);

      float agg = 0.f;
      if (nz) agg = sv[lane] / fmaxf(s_cta[lane], 1.0f);

      float reg = 0.f;
      if (pres) {
        float sq = 0.f;
#pragma unroll
        for (int d = 0; d < 4; d++) sq += s_mean[lane * 4 + d] * s_mean[lane * 4 + d];
        const float nrm = (sq > 0.f) ? sqrtf(sq) : 0.f;
        reg = logf(nrm + 1.0f);
      }

      float dis = 0.f, npair = 0.f;
      for (int pi = lane; pi < LBL * LBL; pi += 64) {
        const int i = pi >> 5, j = pi & 31;
        if (i != j && ((bal_nz >> i) & 1ull) && ((bal_nz >> j) & 1ull)) {
          float sq = 0.f;
#pragma unroll
          for (int d = 0; d < 4; d++) {
            const float df = s_mean[i * 4 + d] - s_mean[j * 4 + d];
            sq += df * df;
          }
          const float pdist = (sq > 0.f) ? sqrtf(sq) : 0.f;
          const float tt = fmaxf(2.0f * DELTA_DIS - pdist, 0.f);
          dis += logf(fmaf(tt, tt, 1.0f));
          npair += 1.0f;
        }
      }

#pragma unroll
      for (int o = 32; o > 0; o >>= 1) {
        agg += __shfl_down(agg, o);
        reg += __shfl_down(reg, o);
        dis += __shfl_down(dis, o);
        npair += __shfl_down(npair, o);
      }

      if (lane == 0) {
        const float l_agg = agg / fmaxf((float)(num_instance - 1), 1.0f);
        const float l_dis = (num_instance > 2) ? dis / fmaxf(npair, 1.0f) : 0.f;
        const float l_reg = reg / fmaxf((float)num_instance, 1.0f) * REG_W;
        const float loss = l_agg + l_dis + l_reg;
        out[b2] = (num_instance <= 1) ? 0.f : loss;
      }
    }
  }
}

extern "C" void kernel_launch(void* const* d_in, const int* in_sizes, int n_in,
                              void* d_out, int out_size, void* d_ws,
                              size_t ws_size, hipStream_t stream) {
  const float* emb = (const float*)d_in[0];
  const int* instance = (const int*)d_in[1];
  const float* kern = (const float*)d_in[2];
  const float* mask = (const float*)d_in[3];
  float* out = (float*)d_out;
  float* ws = (float*)d_ws;

  // zero the 3 barrier counters (stream-ordered, graph-capture-safe)
  hipMemsetAsync((char*)d_ws + (size_t)FBAR_BASE * 4, 0, 12, stream);

  dim3 grid(NBB, BATCH);  // 712 blocks; co-resident by construction (<=768)
  kF<<<grid, 256, 0, stream>>>(emb, instance, kern, mask, ws, out);
}